// Round 7
// baseline (213.980 us; speedup 1.0000x reference)
//
#include <hip/hip_runtime.h>

static constexpr int OHW = 12, NSP = 144;

// ---------------------------------------------------------------------------
// build_T: gather x (4,256,14,14) -> T[n][k][i], n = b*144+oh*12+ow,
// k = (kh*3+kw)*32 + ic, i in [0,8). One float4 (4 consecutive i) per thread.
// ---------------------------------------------------------------------------
__global__ void build_T(const float* __restrict__ x, float4* __restrict__ T4) {
    const int g = blockIdx.x * 256 + threadIdx.x;   // [0, 576*576)
    const int n = g / 576;                          // 576 float4 per n
    const int q = g - n * 576;
    const int r = q << 2;                           // float offset in row
    const int k = r >> 3;
    const int i0 = r & 7;                           // 0 or 4
    const int ic = k & 31;
    const int kk = k >> 5;
    const int kh = kk / 3, kw = kk - kh * 3;
    const int b = n / NSP;
    const int rm = n - b * NSP;
    const int oh = rm / OHW, ow = rm - oh * OHW;
    const float* xp = x + (size_t)(b * 256 + ic * 8 + i0) * 196
                        + (oh + kh) * 14 + (ow + kw);
    float4 v;
    v.x = xp[0];
    v.y = xp[196];
    v.z = xp[392];
    v.w = xp[588];
    T4[g] = v;
}

__device__ __forceinline__ void fma4(float4& a, float s, const float4& w) {
    a.x = fmaf(s, w.x, a.x);
    a.y = fmaf(s, w.y, a.y);
    a.z = fmaf(s, w.z, a.z);
    a.w = fmaf(s, w.w, a.w);
}

// ---- DPP helpers: reductions on the VALU pipe (not LDS/ds_swizzle) ----
template <int CTRL>
__device__ __forceinline__ float dppf(float x) {
    return __int_as_float(__builtin_amdgcn_update_dpp(
        0, __float_as_int(x), CTRL, 0xF, 0xF, true));
}
// sum over the cg quad (lane bits 0,1): quad_perm xor1 (0xB1), xor2 (0x4E)
__device__ __forceinline__ float quad_sum_cg(float x) {
    x += dppf<0xB1>(x);
    x += dppf<0x4E>(x);
    return x;
}
// sum over kgp groups within a 16-lane row (lane bits 2,3): row_ror 4, 8
// (rotation-sum == xor-sum for addition; per-lane order differs by ulps only)
__device__ __forceinline__ float row_sum_kgp(float x) {
    x += dppf<0x124>(x);
    x += dppf<0x128>(x);
    return x;
}

// ---------------------------------------------------------------------------
// caps_main: block = (o, 8 n). 512 threads = 8 waves. R6 structure.
// Phase 1: thread = (cg, kg in [0,128)); chunks k = kg, kg+128, kg+256
//   (kg<32); each (k,cg) weight quad loaded once, amortized over 8 n;
//   write addr = base + lane (conflict-free b128); the m==wv value is read
//   back by the SAME thread, so it stays in a register (skips 1/8 of the
//   P round-trip).
// Phase 2: wave = one n; lane (cg,kgp) owns k = kgp+16*jj, jj in [0,18).
//   All intra-row reductions via DPP (VALU); only strides 16/32 use
//   ds_swizzle. DS-pipe ops/wave: 134 -> 28 (R6 was DS-pipe-bound).
// ---------------------------------------------------------------------------
__global__ __launch_bounds__(512, 3)
void caps_main(const float4* __restrict__ T4, const float4* __restrict__ W4,
               float* __restrict__ out) {
    __shared__ float4 Pl[8 * 8 * 64];        // 65,536 B -> 2 blocks/CU

    const int tid   = threadIdx.x;
    const int o     = blockIdx.y;
    const int nbase = blockIdx.x * 8;
    const int cg    = tid & 3;
    const int kg    = tid >> 2;              // [0,128)
    const int wv    = tid >> 6;              // [0,8)  == kg>>4
    const int lane  = tid & 63;

    float4 P[18];

    // -------- phase-1 producer for one k (8-n amortized weight load) --------
    auto produce = [&](int k, float4& self) {
        float4 w[8];
        const float4* wp = W4 + (size_t)(o * 288 + k) * 32 + cg;
        #pragma unroll
        for (int i = 0; i < 8; ++i) w[i] = wp[i * 4];
        #pragma unroll
        for (int m = 0; m < 8; ++m) {
            const float4* tp = T4 + (size_t)(nbase + m) * 576 + k * 2;
            const float4 t0 = tp[0];
            const float4 t1 = tp[1];
            float4 a = make_float4(0.f, 0.f, 0.f, 0.f);
            fma4(a, t0.x, w[0]); fma4(a, t0.y, w[1]);
            fma4(a, t0.z, w[2]); fma4(a, t0.w, w[3]);
            fma4(a, t1.x, w[4]); fma4(a, t1.y, w[5]);
            fma4(a, t1.z, w[6]); fma4(a, t1.w, w[7]);
            if (m == wv) self = a;                    // own-wave value: keep
            else Pl[m * 512 + wv * 64 + lane] = a;    // addr = base + lane
        }
    };

    const float4* Pn = &Pl[wv * 512];        // phase-2 read base (wave = n)

    // ---- chunk 0: k = kg, slabs jj 0..7 (jj==wv kept in reg) ----
    produce(kg, P[wv]);
    __syncthreads();
    #pragma unroll
    for (int s = 0; s < 8; ++s)
        if (s != wv) P[s] = Pn[s * 64 + lane];
    __syncthreads();

    // ---- chunk 1: k = kg+128, slabs jj 8..15 ----
    produce(kg + 128, P[8 + wv]);
    __syncthreads();
    #pragma unroll
    for (int s = 0; s < 8; ++s)
        if (s != wv) P[8 + s] = Pn[s * 64 + lane];
    __syncthreads();

    // ---- chunk 2 (tail): k = kg+256, kg<32 (waves 0,1), slabs jj 16,17 ----
    if (kg < 32) produce(kg + 256, P[16 + wv]);
    __syncthreads();
    if (wv != 0) P[16] = Pn[lane];
    if (wv != 1) P[17] = Pn[64 + lane];

    // -------- phase 2: dynamic routing (wave = n) --------
    float lj[18];
    #pragma unroll
    for (int jj = 0; jj < 18; ++jj) lj[jj] = 0.f;
    float4 vq = make_float4(0.f, 0.f, 0.f, 0.f);

    #pragma unroll
    for (int it = 0; it < 3; ++it) {
        float4 svU = make_float4(0.f, 0.f, 0.f, 0.f);
        float Sl = 0.f;
        if (it == 0) {
            #pragma unroll
            for (int jj = 0; jj < 18; ++jj) {
                svU.x += P[jj].x; svU.y += P[jj].y;
                svU.z += P[jj].z; svU.w += P[jj].w;
            }
        } else {
            #pragma unroll
            for (int jj = 0; jj < 18; ++jj) {
                const float e = __expf(lj[jj]);   // |lj| <~ 10: safe in fp32
                Sl += e;
                fma4(svU, e, P[jj]);
            }
        }
        // k-reduce: bits 2,3 on VALU (DPP row_ror), bits 4,5 via ds_swizzle
        svU.x = row_sum_kgp(svU.x);
        svU.y = row_sum_kgp(svU.y);
        svU.z = row_sum_kgp(svU.z);
        svU.w = row_sum_kgp(svU.w);
        if (it != 0) Sl = row_sum_kgp(Sl);
        #pragma unroll
        for (int m = 16; m < 64; m <<= 1) {
            svU.x += __shfl_xor(svU.x, m);
            svU.y += __shfl_xor(svU.y, m);
            svU.z += __shfl_xor(svU.z, m);
            svU.w += __shfl_xor(svU.w, m);
            if (it != 0) Sl += __shfl_xor(Sl, m);
        }
        const float S = (it == 0) ? 288.0f : Sl;
        const float invS = __frcp_rn(S);
        float4 s;
        s.x = svU.x * invS; s.y = svU.y * invS;
        s.z = svU.z * invS; s.w = svU.w * invS;
        float sq = s.x * s.x + s.y * s.y + s.z * s.z + s.w * s.w;
        sq = quad_sum_cg(sq);                 // bits 0,1 on VALU
        const float scale = __fsqrt_rn(sq) / (1.0f + sq);
        vq.x = s.x * scale; vq.y = s.y * scale;
        vq.z = s.z * scale; vq.w = s.w * scale;

        if (it < 2) {
            #pragma unroll
            for (int jj = 0; jj < 18; ++jj) {
                float d = P[jj].x * vq.x + P[jj].y * vq.y +
                          P[jj].z * vq.z + P[jj].w * vq.w;
                d = quad_sum_cg(d);           // bits 0,1 on VALU
                lj[jj] += d;
            }
        }
    }

    // -------- store: lanes kgp==0 write their c-quad --------
    if ((lane >> 2) == 0) {
        const int n = nbase + wv;
        const int b = n / NSP;
        const int rm = n - b * NSP;
        float* op = out + (size_t)(b * 512 + o * 16 + cg * 4) * NSP + rm;
        op[0 * NSP] = vq.x;
        op[1 * NSP] = vq.y;
        op[2 * NSP] = vq.z;
        op[3 * NSP] = vq.w;
    }
}

extern "C" void kernel_launch(void* const* d_in, const int* in_sizes, int n_in,
                              void* d_out, int out_size, void* d_ws, size_t ws_size,
                              hipStream_t stream) {
    const float* x  = (const float*)d_in[0];   // (4, 256, 14, 14)
    const float* wt = (const float*)d_in[1];   // (32, 288, 8, 16)
    float* out = (float*)d_out;                // (4, 512, 12, 12)
    float4* T4 = (float4*)d_ws;                // 576*2304 floats = 5.3 MB

    build_T<<<dim3(576 * 576 / 256), 256, 0, stream>>>(x, T4);
    caps_main<<<dim3(72, 32), 512, 0, stream>>>(T4, (const float4*)wt, out);
}